// Round 7
// baseline (657.945 us; speedup 1.0000x reference)
//
#include <hip/hip_runtime.h>
#include <hip/hip_bf16.h>
#include <math.h>

// GraphEncoder: 3x GCNConv (relu) -> global_mean_pool -> two linear heads.
// N=100000, E=1600000, G=2048, feats 10->128->256->256->64(x2)
//
// Round-7 strategy:
//  - agg kernels: persistent grid-stride blocks (2048). Round-6 counters:
//    agg256 occupancy 47%, HBM 48%, VALU 26% -> latency-bound because each
//    block lived ~2 loop iterations (8 nodes); ramp/drain dominated residency.
//  - fill_csr dst-sliced (round-6, confirmed win), MFMA transforms (round-4),
//    bf16 activations (round-3), aggregate-then-transform (round-2) unchanged.

#define THREADS 256

typedef __attribute__((ext_vector_type(8))) short bf16x8;
typedef __attribute__((ext_vector_type(4))) float f32x4;

// ---------------- fused setup: deg=1, gcnt=0, W2T, W3T ----------------
__global__ void setup_kernel(int* deg, int* gcnt,
                             const float* __restrict__ W2, __hip_bfloat16* __restrict__ W2T,
                             const float* __restrict__ W3, __hip_bfloat16* __restrict__ W3T,
                             int n, int g) {
    int i = blockIdx.x * blockDim.x + threadIdx.x;
    if (i < n) deg[i] = 1;                       // self-loop
    int r1 = i - n;
    if (r1 >= 0 && r1 < g) gcnt[r1] = 0;
    int r2 = i - n - g;
    if (r2 >= 0 && r2 < 128 * 256) {
        int k = r2 >> 8, c = r2 & 255;
        W2T[c * 128 + k] = __float2bfloat16(W2[r2]);
    }
    int r3 = i - n - g - 128 * 256;
    if (r3 >= 0 && r3 < 256 * 256) {
        int k = r3 >> 8, c = r3 & 255;
        W3T[c * 256 + k] = __float2bfloat16(W3[r3]);
    }
}

// ---------------- fused histograms: indegree + graph sizes ----------------
__global__ void hist_kernel(const int* __restrict__ dst, int* deg, int e,
                            const int* __restrict__ batch, int* gcnt, int n) {
    int i = blockIdx.x * blockDim.x + threadIdx.x;
    if (i < e) {
        atomicAdd(&deg[dst[i]], 1);
    } else {
        int j = i - e;
        if (j < n) atomicAdd(&gcnt[batch[j]], 1);
    }
}

// ---------------- fused scans ----------------
__device__ void scan_phase(const int* __restrict__ in, int* __restrict__ out,
                           int n, int sub, int* wsum,
                           int* __restrict__ cursor, float* __restrict__ dis) {
    int carry = 0;
    const int lane = threadIdx.x & 63;
    const int wid = threadIdx.x >> 6;
    for (int base = 0; base < n; base += 4096) {
        int i0 = base + threadIdx.x * 4;
        int v[4];
#pragma unroll
        for (int q = 0; q < 4; ++q) {
            int i = i0 + q;
            v[q] = (i < n) ? (in[i] - sub) : 0;
        }
        int tsum = v[0] + v[1] + v[2] + v[3];
        int incl = tsum;
#pragma unroll
        for (int off = 1; off < 64; off <<= 1) {
            int t = __shfl_up(incl, off, 64);
            if (lane >= off) incl += t;
        }
        if (lane == 63) wsum[wid] = incl;
        __syncthreads();
        int wbase = 0;
        for (int w = 0; w < wid; ++w) wbase += wsum[w];
        int pos = incl - tsum + wbase + carry;
#pragma unroll
        for (int q = 0; q < 4; ++q) {
            int i = i0 + q;
            if (i < n) {
                out[i] = pos;
                if (cursor) cursor[i] = pos;
                if (dis) dis[i] = rsqrtf((float)(v[q] + sub));
            }
            pos += v[q];
        }
        int tot = 0;
        for (int w = 0; w < 16; ++w) tot += wsum[w];
        carry += tot;
        __syncthreads();
    }
    if (threadIdx.x == 0) out[n] = carry;
}

__global__ __launch_bounds__(1024) void scan_all_kernel(
        const int* deg, int* row_ptr, int* cursor, float* dis, int n,
        const int* gcnt, int* goff, int g) {
    __shared__ int wsum[16];
    scan_phase(deg, row_ptr, n, 1, wsum, cursor, dis);   // indeg scan + dis + cursor
    __syncthreads();
    scan_phase(gcnt, goff, g, 0, wsum, nullptr, nullptr);
}

// ---------------- dst-sliced CSR fill ----------------
__global__ __launch_bounds__(THREADS) void fill_csr_kernel(
        const int* __restrict__ src, const int* __restrict__ dst,
        int* cursor, int* __restrict__ col, int e, int n) {
    const int nslice = 8;
    const int sliceSize = (n + nslice - 1) / nslice;
    const int tid = blockIdx.x * blockDim.x + threadIdx.x;
    const int nthr = gridDim.x * blockDim.x;
    for (int s = 0; s < nslice; ++s) {
        const int lo = s * sliceSize;
        const int hi = lo + sliceSize;
        for (int i = tid; i < e; i += nthr) {
            int d = dst[i];
            if (d >= lo && d < hi) {
                int pos = atomicAdd(&cursor[d], 1);
                col[pos] = src[i];
            }
        }
    }
}

// ---------------- agg over 10-col f32 rows, inline x*dis (16 lanes/node) ----------------
__global__ __launch_bounds__(THREADS) void agg10_kernel(
        const float* __restrict__ x, const int* __restrict__ row_ptr,
        const int* __restrict__ col, const float* __restrict__ dis,
        float* __restrict__ out, int n) {
    const int ngroups = (n + 15) / 16;
    for (int blk = blockIdx.x; blk < ngroups; blk += gridDim.x) {
        int node = blk * 16 + threadIdx.x / 16;
        if (node >= n) continue;
        int lane = threadIdx.x % 16;
        bool act = lane < 10;
        float dn = dis[node];
        float acc = act ? x[(size_t)node * 10 + lane] * dn : 0.f;
        int s = row_ptr[node], e = row_ptr[node + 1];
        int p = s;
        for (; p + 4 <= e; p += 4) {
            int j[4];
#pragma unroll
            for (int q = 0; q < 4; ++q) j[q] = col[p + q];
            float v[4];
#pragma unroll
            for (int q = 0; q < 4; ++q)
                v[q] = act ? x[(size_t)j[q] * 10 + lane] * dis[j[q]] : 0.f;
            acc += v[0] + v[1] + v[2] + v[3];
        }
        for (; p < e; ++p) {
            int j = col[p];
            if (act) acc += x[(size_t)j * 10 + lane] * dis[j];
        }
        if (act) out[(size_t)node * 10 + lane] = acc * dn;
    }
}

// ---------------- bf16 helpers ----------------
__device__ __forceinline__ void acc8(float* acc, uint4 v) {
    acc[0] += __uint_as_float(v.x << 16);
    acc[1] += __uint_as_float(v.x & 0xffff0000u);
    acc[2] += __uint_as_float(v.y << 16);
    acc[3] += __uint_as_float(v.y & 0xffff0000u);
    acc[4] += __uint_as_float(v.z << 16);
    acc[5] += __uint_as_float(v.z & 0xffff0000u);
    acc[6] += __uint_as_float(v.w << 16);
    acc[7] += __uint_as_float(v.w & 0xffff0000u);
}

__device__ __forceinline__ unsigned pack2(float a, float b) {
    unsigned short ua = __builtin_bit_cast(unsigned short, __float2bfloat16(a));
    unsigned short ub = __builtin_bit_cast(unsigned short, __float2bfloat16(b));
    return (unsigned)ua | ((unsigned)ub << 16);
}

// ---------------- agg over COLS-col bf16 rows; L = COLS/8 lanes/node ----------------
// persistent grid-stride blocks: amortize block ramp/drain, keep waves resident
template <int COLS, int L>
__global__ __launch_bounds__(THREADS) void agg_bf16_kernel(
        const __hip_bfloat16* __restrict__ S, const int* __restrict__ row_ptr,
        const int* __restrict__ col, const float* __restrict__ dis,
        __hip_bfloat16* __restrict__ out, int n) {
    static_assert(L * 8 == COLS, "");
    constexpr int stride = COLS / 8;       // uint4 per row
    constexpr int NPB = THREADS / L;       // nodes per block-iter
    const uint4* S4 = reinterpret_cast<const uint4*>(S);
    const int ngroups = (n + NPB - 1) / NPB;
    const int lane = threadIdx.x % L;
    const int sub = threadIdx.x / L;

    for (int blk = blockIdx.x; blk < ngroups; blk += gridDim.x) {
        int node = blk * NPB + sub;
        if (node >= n) continue;

        float acc[8];
#pragma unroll
        for (int q = 0; q < 8; ++q) acc[q] = 0.f;
        acc8(acc, S4[(size_t)node * stride + lane]);   // self-loop term

        int s = row_ptr[node], e = row_ptr[node + 1];
        int p = s;
        for (; p + 8 <= e; p += 8) {
            int j[8];
#pragma unroll
            for (int q = 0; q < 8; ++q) j[q] = col[p + q];
            uint4 v[8];
#pragma unroll
            for (int q = 0; q < 8; ++q) v[q] = S4[(size_t)j[q] * stride + lane];
#pragma unroll
            for (int q = 0; q < 8; ++q) acc8(acc, v[q]);
        }
        for (; p + 2 <= e; p += 2) {
            int j0 = col[p], j1 = col[p + 1];
            uint4 v0 = S4[(size_t)j0 * stride + lane];
            uint4 v1 = S4[(size_t)j1 * stride + lane];
            acc8(acc, v0); acc8(acc, v1);
        }
        for (; p < e; ++p) acc8(acc, S4[(size_t)col[p] * stride + lane]);

        float d = dis[node];
        uint4 o;
        o.x = pack2(acc[0] * d, acc[1] * d);
        o.y = pack2(acc[2] * d, acc[3] * d);
        o.z = pack2(acc[4] * d, acc[5] * d);
        o.w = pack2(acc[6] * d, acc[7] * d);
        reinterpret_cast<uint4*>(out)[(size_t)node * stride + lane] = o;
    }
}

// ---------------- layer-1 transform: [N,10]f32 @ [10,128] + b, relu, *dis -> bf16 ----------------
__global__ __launch_bounds__(THREADS) void transform1_kernel(
        const float* __restrict__ A0, const float* __restrict__ W,
        const float* __restrict__ b, const float* __restrict__ dis,
        __hip_bfloat16* __restrict__ out, int n) {
    int t = blockIdx.x * blockDim.x + threadIdx.x;
    if (t >= n * 128) return;
    int r = t >> 7;
    int c = t & 127;
    float acc = b[c];
#pragma unroll
    for (int k = 0; k < 10; ++k)
        acc = fmaf(A0[(size_t)r * 10 + k], W[k * 128 + c], acc);
    out[(size_t)r * 128 + c] = __float2bfloat16(fmaxf(acc, 0.f) * dis[r]);
}

// ---------------- MFMA transform v2: bf16 [N,K] @ WT[256][K] -> bf16 [N,256] ----------------
template <int K, bool SCALE>
__global__ __launch_bounds__(THREADS) void transform_mfma2_kernel(
        const __hip_bfloat16* __restrict__ A, const __hip_bfloat16* __restrict__ WT,
        const float* __restrict__ b, const float* __restrict__ dis,
        __hip_bfloat16* __restrict__ out, int n, int ntiles) {
    constexpr int KS = K / 32;             // 4 (K=128) or 8 (K=256)
    const int wave = threadIdx.x >> 6;
    const int lane = threadIdx.x & 63;
    const int lrow = lane & 15;
    const int lk8  = (lane >> 4) * 8;      // k-element offset within a 32-k step

    const uint4* WT4 = reinterpret_cast<const uint4*>(WT);
    bf16x8 bfr[4][KS];
    float bias[4];
#pragma unroll
    for (int ct = 0; ct < 4; ++ct) {
        int colc = wave * 64 + ct * 16 + lrow;
        bias[ct] = b[colc];
#pragma unroll
        for (int kk = 0; kk < KS; ++kk)
            bfr[ct][kk] = __builtin_bit_cast(
                bf16x8, WT4[((size_t)colc * K + kk * 32 + lk8) >> 3]);
    }

    const uint4* A4 = reinterpret_cast<const uint4*>(A);
    auto loadA = [&](int t, uint4* av) {
        int row = t * 16 + lrow;
        if (row >= n) row = n - 1;
#pragma unroll
        for (int kk = 0; kk < KS; ++kk)
            av[kk] = A4[((size_t)row * K + kk * 32 + lk8) >> 3];
    };

    uint4 aC[KS], aN[KS];
    int t = blockIdx.x;
    if (t < ntiles) loadA(t, aC);

    for (; t < ntiles; t += gridDim.x) {
        int tn = t + gridDim.x;
        if (tn < ntiles) loadA(tn, aN);    // prefetch next tile

        f32x4 acc[4];
#pragma unroll
        for (int ct = 0; ct < 4; ++ct) acc[ct] = (f32x4){0.f, 0.f, 0.f, 0.f};
#pragma unroll
        for (int kk = 0; kk < KS; ++kk) {
            bf16x8 af = __builtin_bit_cast(bf16x8, aC[kk]);
#pragma unroll
            for (int ct = 0; ct < 4; ++ct)
                acc[ct] = __builtin_amdgcn_mfma_f32_16x16x32_bf16(af, bfr[ct][kk], acc[ct], 0, 0, 0);
        }

        const int orow0 = t * 16 + (lane >> 4) * 4;
        float dv[4];
#pragma unroll
        for (int r = 0; r < 4; ++r) {
            int rr = orow0 + r;
            dv[r] = SCALE ? ((rr < n) ? dis[rr] : 0.f) : 1.f;
        }
#pragma unroll
        for (int ct = 0; ct < 4; ++ct) {
            int colc = wave * 64 + ct * 16 + lrow;
#pragma unroll
            for (int r = 0; r < 4; ++r) {
                int rr = orow0 + r;
                if (rr < n) {
                    float v = fmaxf(acc[ct][r] + bias[ct], 0.f);
                    if (SCALE) v *= dv[r];
                    out[(size_t)rr * 256 + colc] = __float2bfloat16(v);
                }
            }
        }
#pragma unroll
        for (int kk = 0; kk < KS; ++kk) aC[kk] = aN[kk];
    }
}

// ---------------- fused mean-pool + heads (pooled in LDS) ----------------
__global__ __launch_bounds__(THREADS) void pool_heads_kernel(
        const __hip_bfloat16* __restrict__ H, const int* __restrict__ goff,
        const float* __restrict__ Wmu, const float* __restrict__ bmu,
        const float* __restrict__ Wlv, const float* __restrict__ blv,
        float* __restrict__ out, int g_total) {
    __shared__ float p[256];
    int g = blockIdx.x;
    int c = threadIdx.x;
    int s = goff[g], e = goff[g + 1];
    float acc = 0.f;
    for (int r = s; r < e; ++r) acc += __bfloat162float(H[(size_t)r * 256 + c]);
    p[c] = acc / fmaxf((float)(e - s), 1.0f);
    __syncthreads();
    if (threadIdx.x < 128) {
        int cc = threadIdx.x & 63;
        bool is_mu = threadIdx.x < 64;
        const float* W = is_mu ? Wmu : Wlv;
        const float* bb = is_mu ? bmu : blv;
        float a = 0.f;
        for (int k = 0; k < 256; ++k) a = fmaf(p[k], W[k * 64 + cc], a);
        float* o = is_mu ? (out + (size_t)g * 64)
                         : (out + (size_t)g_total * 64 + (size_t)g * 64);
        o[cc] = a + bb[cc];
    }
}

extern "C" void kernel_launch(void* const* d_in, const int* in_sizes, int n_in,
                              void* d_out, int out_size, void* d_ws, size_t ws_size,
                              hipStream_t stream) {
    const float* x      = (const float*)d_in[0];
    const int*   eidx   = (const int*)d_in[1];
    const int*   batch  = (const int*)d_in[2];
    const float* W1  = (const float*)d_in[3];
    const float* b1  = (const float*)d_in[4];
    const float* W2  = (const float*)d_in[5];
    const float* b2  = (const float*)d_in[6];
    const float* W3  = (const float*)d_in[7];
    const float* b3  = (const float*)d_in[8];
    const float* Wmu = (const float*)d_in[9];
    const float* bmu = (const float*)d_in[10];
    const float* Wlv = (const float*)d_in[11];
    const float* blv = (const float*)d_in[12];
    float* out = (float*)d_out;

    const int N = in_sizes[0] / 10;
    const int E = in_sizes[1] / 2;
    const int G = out_size / 128;

    const int* src = eidx;       // edge_index[0]
    const int* dst = eidx + E;   // edge_index[1]

    // workspace carve-up (~118 MB)
    __hip_bfloat16* SA = (__hip_bfloat16*)d_ws;          // [N,256] bf16 ping
    __hip_bfloat16* SB = SA + (size_t)N * 256;           // [N,256] bf16 pong
    float* B0   = (float*)(SB + (size_t)N * 256);        // [N,10] agg out
    float* dis  = B0 + (size_t)N * 10;                   // [N]
    __hip_bfloat16* W2T = (__hip_bfloat16*)(dis + N);    // [256][128]
    __hip_bfloat16* W3T = W2T + 256 * 128;               // [256][256]
    int* deg     = (int*)(W3T + 256 * 256);              // [N]
    int* row_ptr = deg + N;                              // [N+1]
    int* cursor  = row_ptr + N + 1;                      // [N]
    int* col     = cursor + N;                           // [E]
    int* gcnt    = col + E;                              // [G]
    int* goff    = gcnt + G;                             // [G+1]

    const int ntiles = (N + 15) / 16;

    // setup: deg=1, gcnt=0, W transposes
    {
        int total = N + G + 128 * 256 + 256 * 256;
        setup_kernel<<<(total + THREADS - 1) / THREADS, THREADS, 0, stream>>>(
            deg, gcnt, W2, W2T, W3, W3T, N, G);
    }
    // histograms: indegree + graph sizes
    {
        int total = E + N;
        hist_kernel<<<(total + THREADS - 1) / THREADS, THREADS, 0, stream>>>(
            dst, deg, E, batch, gcnt, N);
    }
    // scans: row_ptr (+cursor, +dis) and goff
    scan_all_kernel<<<1, 1024, 0, stream>>>(deg, row_ptr, cursor, dis, N, gcnt, goff, G);
    // dst-sliced CSR fill
    fill_csr_kernel<<<2048, THREADS, 0, stream>>>(src, dst, cursor, col, E, N);

    // layer 1: aggregate x*dis (10 f32 cols, inline) then transform 10->128 -> bf16
    agg10_kernel<<<2048, THREADS, 0, stream>>>(x, row_ptr, col, dis, B0, N);
    transform1_kernel<<<((size_t)N * 128 + THREADS - 1) / THREADS, THREADS, 0, stream>>>(B0, W1, b1, dis, SA, N);

    // layer 2: aggregate S1 (128 bf16 cols) then MFMA transform 128->256 (*dis)
    agg_bf16_kernel<128, 16><<<2048, THREADS, 0, stream>>>(SA, row_ptr, col, dis, SB, N);
    transform_mfma2_kernel<128, true><<<512, THREADS, 0, stream>>>(SB, W2T, b2, dis, SA, N, ntiles);

    // layer 3: aggregate S2 (256 bf16 cols) then MFMA transform 256->256
    agg_bf16_kernel<256, 32><<<2048, THREADS, 0, stream>>>(SA, row_ptr, col, dis, SB, N);
    transform_mfma2_kernel<256, false><<<512, THREADS, 0, stream>>>(SB, W3T, b3, dis, SA, N, ntiles);

    // fused mean pool + heads
    pool_heads_kernel<<<G, THREADS, 0, stream>>>(SA, goff, Wmu, bmu, Wlv, blv, out, G);
}

// Round 8
// 599.224 us; speedup vs baseline: 1.0980x; 1.0980x over previous
//
#include <hip/hip_runtime.h>
#include <hip/hip_bf16.h>
#include <math.h>

// GraphEncoder: 3x GCNConv (relu) -> global_mean_pool -> two linear heads.
// N=100000, E=1600000, G=2048, feats 10->128->256->256->64(x2)
//
// Round-8 strategy:
//  - agg kernels: exact grids (round-7 persistence REGRESSED: agg256 118->127,
//    occupancy 47->42; gather is at the 8xXCD L2-refill traffic floor
//    (FETCH ~= 8 x 51MB), not wave-starved).
//  - fill_csr: 4 slices (was 8) - halves repeated edge-stream reads, window
//    (1.7MB col+cursor) still per-XCD-L2-resident.
//  - goff computed from sorted-batch boundaries (no atomics, no 2nd scan).
//  - agg10+transform1 fused (gather rows + W1 in LDS, uint4 bf16 stores).

#define THREADS 256

typedef __attribute__((ext_vector_type(8))) short bf16x8;
typedef __attribute__((ext_vector_type(4))) float f32x4;

// ---------------- fused setup: deg=1, W2T, W3T ----------------
__global__ void setup_kernel(int* deg,
                             const float* __restrict__ W2, __hip_bfloat16* __restrict__ W2T,
                             const float* __restrict__ W3, __hip_bfloat16* __restrict__ W3T,
                             int n) {
    int i = blockIdx.x * blockDim.x + threadIdx.x;
    if (i < n) deg[i] = 1;                       // self-loop
    int r2 = i - n;
    if (r2 >= 0 && r2 < 128 * 256) {
        int k = r2 >> 8, c = r2 & 255;
        W2T[c * 128 + k] = __float2bfloat16(W2[r2]);
    }
    int r3 = i - n - 128 * 256;
    if (r3 >= 0 && r3 < 256 * 256) {
        int k = r3 >> 8, c = r3 & 255;
        W3T[c * 256 + k] = __float2bfloat16(W3[r3]);
    }
}

// ---------------- indegree hist + goff from sorted-batch boundaries ----------------
__global__ void hist_bound_kernel(const int* __restrict__ dst, int* deg, int e,
                                  const int* __restrict__ batch, int* goff,
                                  int n, int g) {
    int i = blockIdx.x * blockDim.x + threadIdx.x;
    if (i < e) {
        atomicAdd(&deg[dst[i]], 1);
    } else {
        int j = i - e;
        if (j < n) {
            int b = batch[j];
            if (j == 0) {
                for (int q = 0; q <= b; ++q) goff[q] = 0;
            } else {
                int bp = batch[j - 1];
                for (int q = bp + 1; q <= b; ++q) goff[q] = j;
            }
            if (j == n - 1) {
                for (int q = b + 1; q <= g; ++q) goff[q] = n;
            }
        }
    }
}

// ---------------- single-phase scan: row_ptr (+cursor, +dis) ----------------
__global__ __launch_bounds__(1024) void scan_deg_kernel(
        const int* __restrict__ deg, int* __restrict__ row_ptr,
        int* __restrict__ cursor, float* __restrict__ dis, int n) {
    __shared__ int wsum[16];
    int carry = 0;
    const int lane = threadIdx.x & 63;
    const int wid = threadIdx.x >> 6;
    for (int base = 0; base < n; base += 4096) {
        int i0 = base + threadIdx.x * 4;
        int v[4];
#pragma unroll
        for (int q = 0; q < 4; ++q) {
            int i = i0 + q;
            v[q] = (i < n) ? (deg[i] - 1) : 0;   // indegree
        }
        int tsum = v[0] + v[1] + v[2] + v[3];
        int incl = tsum;
#pragma unroll
        for (int off = 1; off < 64; off <<= 1) {
            int t = __shfl_up(incl, off, 64);
            if (lane >= off) incl += t;
        }
        if (lane == 63) wsum[wid] = incl;
        __syncthreads();
        int wbase = 0;
        for (int w = 0; w < wid; ++w) wbase += wsum[w];
        int pos = incl - tsum + wbase + carry;
#pragma unroll
        for (int q = 0; q < 4; ++q) {
            int i = i0 + q;
            if (i < n) {
                row_ptr[i] = pos;
                cursor[i] = pos;
                dis[i] = rsqrtf((float)(v[q] + 1));
            }
            pos += v[q];
        }
        int tot = 0;
        for (int w = 0; w < 16; ++w) tot += wsum[w];
        carry += tot;
        __syncthreads();
    }
    if (threadIdx.x == 0) row_ptr[n] = carry;
}

// ---------------- dst-sliced CSR fill (4 slices) ----------------
__global__ __launch_bounds__(THREADS) void fill_csr_kernel(
        const int* __restrict__ src, const int* __restrict__ dst,
        int* cursor, int* __restrict__ col, int e, int n) {
    const int nslice = 4;
    const int sliceSize = (n + nslice - 1) / nslice;
    const int tid = blockIdx.x * blockDim.x + threadIdx.x;
    const int nthr = gridDim.x * blockDim.x;
    for (int s = 0; s < nslice; ++s) {
        const int lo = s * sliceSize;
        const int hi = lo + sliceSize;
        for (int i = tid; i < e; i += nthr) {
            int d = dst[i];
            if (d >= lo && d < hi) {
                int pos = atomicAdd(&cursor[d], 1);
                col[pos] = src[i];
            }
        }
    }
}

// ---------------- bf16 helpers ----------------
__device__ __forceinline__ void acc8(float* acc, uint4 v) {
    acc[0] += __uint_as_float(v.x << 16);
    acc[1] += __uint_as_float(v.x & 0xffff0000u);
    acc[2] += __uint_as_float(v.y << 16);
    acc[3] += __uint_as_float(v.y & 0xffff0000u);
    acc[4] += __uint_as_float(v.z << 16);
    acc[5] += __uint_as_float(v.z & 0xffff0000u);
    acc[6] += __uint_as_float(v.w << 16);
    acc[7] += __uint_as_float(v.w & 0xffff0000u);
}

__device__ __forceinline__ unsigned pack2(float a, float b) {
    unsigned short ua = __builtin_bit_cast(unsigned short, __float2bfloat16(a));
    unsigned short ub = __builtin_bit_cast(unsigned short, __float2bfloat16(b));
    return (unsigned)ua | ((unsigned)ub << 16);
}

// ---------------- fused layer 1: agg over 10-col x rows + 10->128 transform ----------------
// Block = 16 nodes. Phase A: 16-lane groups gather x*dis rows -> LDS.
// Phase B: thread (r, c0/8) computes 8 output cols via W1 in LDS, uint4 store.
__global__ __launch_bounds__(THREADS) void layer1_kernel(
        const float* __restrict__ x, const int* __restrict__ row_ptr,
        const int* __restrict__ col, const float* __restrict__ dis,
        const float* __restrict__ W1, const float* __restrict__ b1,
        __hip_bfloat16* __restrict__ out, int n) {
    __shared__ float h[16][12];
    __shared__ float w[10][128];
    __shared__ float bias[128];

    for (int idx = threadIdx.x; idx < 1280; idx += THREADS)
        w[idx >> 7][idx & 127] = W1[idx];
    if (threadIdx.x < 128) bias[threadIdx.x] = b1[threadIdx.x];

    const int node0 = blockIdx.x * 16;
    const int sub = threadIdx.x >> 4;
    const int lane = threadIdx.x & 15;
    const int node = node0 + sub;
    const bool act = (lane < 10) && (node < n);

    float acc = 0.f;
    float dn = 1.f;
    if (act) {
        dn = dis[node];
        acc = x[(size_t)node * 10 + lane] * dn;
        int s = row_ptr[node], e = row_ptr[node + 1];
        int p = s;
        for (; p + 8 <= e; p += 8) {
            int j[8];
#pragma unroll
            for (int q = 0; q < 8; ++q) j[q] = col[p + q];
            float v[8];
#pragma unroll
            for (int q = 0; q < 8; ++q) v[q] = x[(size_t)j[q] * 10 + lane] * dis[j[q]];
#pragma unroll
            for (int q = 0; q < 8; ++q) acc += v[q];
        }
        for (; p < e; ++p) {
            int j = col[p];
            acc += x[(size_t)j * 10 + lane] * dis[j];
        }
        acc *= dn;
    }
    if (lane < 12) h[sub][lane] = (lane < 10) ? acc : 0.f;
    __syncthreads();

    const int r = threadIdx.x >> 4;
    const int c0 = (threadIdx.x & 15) * 8;
    const int nodeB = node0 + r;
    if (nodeB < n) {
        float dnB = dis[nodeB];
        float hv[10];
#pragma unroll
        for (int k = 0; k < 10; ++k) hv[k] = h[r][k];
        uint4 res;
        unsigned rr[4];
#pragma unroll
        for (int cc = 0; cc < 8; cc += 2) {
            float a0 = bias[c0 + cc], a1 = bias[c0 + cc + 1];
#pragma unroll
            for (int k = 0; k < 10; ++k) {
                a0 = fmaf(hv[k], w[k][c0 + cc], a0);
                a1 = fmaf(hv[k], w[k][c0 + cc + 1], a1);
            }
            rr[cc >> 1] = pack2(fmaxf(a0, 0.f) * dnB, fmaxf(a1, 0.f) * dnB);
        }
        res.x = rr[0]; res.y = rr[1]; res.z = rr[2]; res.w = rr[3];
        reinterpret_cast<uint4*>(out)[((size_t)nodeB * 128 + c0) >> 3] = res;
    }
}

// ---------------- agg over COLS-col bf16 rows; L = COLS/8 lanes/node ----------------
template <int COLS, int L>
__global__ __launch_bounds__(THREADS) void agg_bf16_kernel(
        const __hip_bfloat16* __restrict__ S, const int* __restrict__ row_ptr,
        const int* __restrict__ col, const float* __restrict__ dis,
        __hip_bfloat16* __restrict__ out, int n) {
    static_assert(L * 8 == COLS, "");
    constexpr int stride = COLS / 8;       // uint4 per row
    int node = blockIdx.x * (THREADS / L) + threadIdx.x / L;
    if (node >= n) return;
    int lane = threadIdx.x % L;
    const uint4* S4 = reinterpret_cast<const uint4*>(S);

    float acc[8];
#pragma unroll
    for (int q = 0; q < 8; ++q) acc[q] = 0.f;
    acc8(acc, S4[(size_t)node * stride + lane]);   // self-loop term

    int s = row_ptr[node], e = row_ptr[node + 1];
    int p = s;
    for (; p + 8 <= e; p += 8) {
        int j[8];
#pragma unroll
        for (int q = 0; q < 8; ++q) j[q] = col[p + q];
        uint4 v[8];
#pragma unroll
        for (int q = 0; q < 8; ++q) v[q] = S4[(size_t)j[q] * stride + lane];
#pragma unroll
        for (int q = 0; q < 8; ++q) acc8(acc, v[q]);
    }
    for (; p + 2 <= e; p += 2) {
        int j0 = col[p], j1 = col[p + 1];
        uint4 v0 = S4[(size_t)j0 * stride + lane];
        uint4 v1 = S4[(size_t)j1 * stride + lane];
        acc8(acc, v0); acc8(acc, v1);
    }
    for (; p < e; ++p) acc8(acc, S4[(size_t)col[p] * stride + lane]);

    float d = dis[node];
    uint4 o;
    o.x = pack2(acc[0] * d, acc[1] * d);
    o.y = pack2(acc[2] * d, acc[3] * d);
    o.z = pack2(acc[4] * d, acc[5] * d);
    o.w = pack2(acc[6] * d, acc[7] * d);
    reinterpret_cast<uint4*>(out)[(size_t)node * stride + lane] = o;
}

// ---------------- MFMA transform v2: bf16 [N,K] @ WT[256][K] -> bf16 [N,256] ----------------
template <int K, bool SCALE>
__global__ __launch_bounds__(THREADS) void transform_mfma2_kernel(
        const __hip_bfloat16* __restrict__ A, const __hip_bfloat16* __restrict__ WT,
        const float* __restrict__ b, const float* __restrict__ dis,
        __hip_bfloat16* __restrict__ out, int n, int ntiles) {
    constexpr int KS = K / 32;             // 4 (K=128) or 8 (K=256)
    const int wave = threadIdx.x >> 6;
    const int lane = threadIdx.x & 63;
    const int lrow = lane & 15;
    const int lk8  = (lane >> 4) * 8;      // k-element offset within a 32-k step

    const uint4* WT4 = reinterpret_cast<const uint4*>(WT);
    bf16x8 bfr[4][KS];
    float bias[4];
#pragma unroll
    for (int ct = 0; ct < 4; ++ct) {
        int colc = wave * 64 + ct * 16 + lrow;
        bias[ct] = b[colc];
#pragma unroll
        for (int kk = 0; kk < KS; ++kk)
            bfr[ct][kk] = __builtin_bit_cast(
                bf16x8, WT4[((size_t)colc * K + kk * 32 + lk8) >> 3]);
    }

    const uint4* A4 = reinterpret_cast<const uint4*>(A);
    auto loadA = [&](int t, uint4* av) {
        int row = t * 16 + lrow;
        if (row >= n) row = n - 1;
#pragma unroll
        for (int kk = 0; kk < KS; ++kk)
            av[kk] = A4[((size_t)row * K + kk * 32 + lk8) >> 3];
    };

    uint4 aC[KS], aN[KS];
    int t = blockIdx.x;
    if (t < ntiles) loadA(t, aC);

    for (; t < ntiles; t += gridDim.x) {
        int tn = t + gridDim.x;
        if (tn < ntiles) loadA(tn, aN);    // prefetch next tile

        f32x4 acc[4];
#pragma unroll
        for (int ct = 0; ct < 4; ++ct) acc[ct] = (f32x4){0.f, 0.f, 0.f, 0.f};
#pragma unroll
        for (int kk = 0; kk < KS; ++kk) {
            bf16x8 af = __builtin_bit_cast(bf16x8, aC[kk]);
#pragma unroll
            for (int ct = 0; ct < 4; ++ct)
                acc[ct] = __builtin_amdgcn_mfma_f32_16x16x32_bf16(af, bfr[ct][kk], acc[ct], 0, 0, 0);
        }

        const int orow0 = t * 16 + (lane >> 4) * 4;
        float dv[4];
#pragma unroll
        for (int r = 0; r < 4; ++r) {
            int rr = orow0 + r;
            dv[r] = SCALE ? ((rr < n) ? dis[rr] : 0.f) : 1.f;
        }
#pragma unroll
        for (int ct = 0; ct < 4; ++ct) {
            int colc = wave * 64 + ct * 16 + lrow;
#pragma unroll
            for (int r = 0; r < 4; ++r) {
                int rr = orow0 + r;
                if (rr < n) {
                    float v = fmaxf(acc[ct][r] + bias[ct], 0.f);
                    if (SCALE) v *= dv[r];
                    out[(size_t)rr * 256 + colc] = __float2bfloat16(v);
                }
            }
        }
#pragma unroll
        for (int kk = 0; kk < KS; ++kk) aC[kk] = aN[kk];
    }
}

// ---------------- fused mean-pool + heads (pooled in LDS) ----------------
__global__ __launch_bounds__(THREADS) void pool_heads_kernel(
        const __hip_bfloat16* __restrict__ H, const int* __restrict__ goff,
        const float* __restrict__ Wmu, const float* __restrict__ bmu,
        const float* __restrict__ Wlv, const float* __restrict__ blv,
        float* __restrict__ out, int g_total) {
    __shared__ float p[256];
    int g = blockIdx.x;
    int c = threadIdx.x;
    int s = goff[g], e = goff[g + 1];
    float acc = 0.f;
    for (int r = s; r < e; ++r) acc += __bfloat162float(H[(size_t)r * 256 + c]);
    p[c] = acc / fmaxf((float)(e - s), 1.0f);
    __syncthreads();
    if (threadIdx.x < 128) {
        int cc = threadIdx.x & 63;
        bool is_mu = threadIdx.x < 64;
        const float* W = is_mu ? Wmu : Wlv;
        const float* bb = is_mu ? bmu : blv;
        float a = 0.f;
        for (int k = 0; k < 256; ++k) a = fmaf(p[k], W[k * 64 + cc], a);
        float* o = is_mu ? (out + (size_t)g * 64)
                         : (out + (size_t)g_total * 64 + (size_t)g * 64);
        o[cc] = a + bb[cc];
    }
}

extern "C" void kernel_launch(void* const* d_in, const int* in_sizes, int n_in,
                              void* d_out, int out_size, void* d_ws, size_t ws_size,
                              hipStream_t stream) {
    const float* x      = (const float*)d_in[0];
    const int*   eidx   = (const int*)d_in[1];
    const int*   batch  = (const int*)d_in[2];
    const float* W1  = (const float*)d_in[3];
    const float* b1  = (const float*)d_in[4];
    const float* W2  = (const float*)d_in[5];
    const float* b2  = (const float*)d_in[6];
    const float* W3  = (const float*)d_in[7];
    const float* b3  = (const float*)d_in[8];
    const float* Wmu = (const float*)d_in[9];
    const float* bmu = (const float*)d_in[10];
    const float* Wlv = (const float*)d_in[11];
    const float* blv = (const float*)d_in[12];
    float* out = (float*)d_out;

    const int N = in_sizes[0] / 10;
    const int E = in_sizes[1] / 2;
    const int G = out_size / 128;

    const int* src = eidx;       // edge_index[0]
    const int* dst = eidx + E;   // edge_index[1]

    // workspace carve-up (~118 MB)
    __hip_bfloat16* SA = (__hip_bfloat16*)d_ws;          // [N,256] bf16 ping
    __hip_bfloat16* SB = SA + (size_t)N * 256;           // [N,256] bf16 pong
    float* dis  = (float*)(SB + (size_t)N * 256);        // [N]
    __hip_bfloat16* W2T = (__hip_bfloat16*)(dis + N);    // [256][128]
    __hip_bfloat16* W3T = W2T + 256 * 128;               // [256][256]
    int* deg     = (int*)(W3T + 256 * 256);              // [N]
    int* row_ptr = deg + N;                              // [N+1]
    int* cursor  = row_ptr + N + 1;                      // [N]
    int* col     = cursor + N;                           // [E]
    int* goff    = col + E;                              // [G+1]

    const int ntiles = (N + 15) / 16;

    // setup: deg=1, W transposes
    {
        int total = N + 128 * 256 + 256 * 256;
        setup_kernel<<<(total + THREADS - 1) / THREADS, THREADS, 0, stream>>>(
            deg, W2, W2T, W3, W3T, N);
    }
    // indegree hist + goff boundaries
    {
        int total = E + N;
        hist_bound_kernel<<<(total + THREADS - 1) / THREADS, THREADS, 0, stream>>>(
            dst, deg, E, batch, goff, N, G);
    }
    // scan: row_ptr (+cursor, +dis)
    scan_deg_kernel<<<1, 1024, 0, stream>>>(deg, row_ptr, cursor, dis, N);
    // dst-sliced CSR fill (4 slices)
    fill_csr_kernel<<<2048, THREADS, 0, stream>>>(src, dst, cursor, col, E, N);

    // layer 1: fused gather(x*dis) + 10->128 transform -> bf16 (*dis)
    layer1_kernel<<<(N + 15) / 16, THREADS, 0, stream>>>(
        x, row_ptr, col, dis, W1, b1, SA, N);

    // layer 2: aggregate S1 (128 bf16 cols) then MFMA transform 128->256 (*dis)
    agg_bf16_kernel<128, 16><<<(N + 15) / 16, THREADS, 0, stream>>>(SA, row_ptr, col, dis, SB, N);
    transform_mfma2_kernel<128, true><<<512, THREADS, 0, stream>>>(SB, W2T, b2, dis, SA, N, ntiles);

    // layer 3: aggregate S2 (256 bf16 cols) then MFMA transform 256->256
    agg_bf16_kernel<256, 32><<<(N + 7) / 8, THREADS, 0, stream>>>(SA, row_ptr, col, dis, SB, N);
    transform_mfma2_kernel<256, false><<<512, THREADS, 0, stream>>>(SB, W3T, b3, dis, SA, N, ntiles);

    // fused mean pool + heads
    pool_heads_kernel<<<G, THREADS, 0, stream>>>(SA, goff, Wmu, bmu, Wlv, blv, out, G);
}